// Round 1
// baseline (139.586 us; speedup 1.0000x reference)
//
#include <hip/hip_runtime.h>

constexpr int BN = 262144;
constexpr int H_ = 100;

__device__ __forceinline__ float softplus_f(float x) {
    // |preact| <= ~6 for this data; direct form is safe for x < 88
    return __logf(1.0f + __expf(x));
}

__global__ __launch_bounds__(256) void sde_fused(
    const float* __restrict__ zt1, const float* __restrict__ zt2,
    const float* __restrict__ dtp,
    const float* __restrict__ W1m, const float* __restrict__ b1m,
    const float* __restrict__ W2m, const float* __restrict__ b2m,
    const float* __restrict__ W1d, const float* __restrict__ b1d,
    const float* __restrict__ W2d, const float* __restrict__ b2d,
    float* __restrict__ out)
{
    const int i = blockIdx.x * blockDim.x + threadIdx.x;
    const float dt0  = dtp[0];
    const float sqdt = sqrtf(dt0);

    // load zt1 row (2x float4, coalesced)
    float x[8];
    {
        const float4* p = reinterpret_cast<const float4*>(zt1) + (size_t)i * 2;
        float4 a = p[0], b = p[1];
        x[0]=a.x; x[1]=a.y; x[2]=a.z; x[3]=a.w;
        x[4]=b.x; x[5]=b.y; x[6]=b.z; x[7]=b.w;
    }

    float am[8], ad[8];
    #pragma unroll
    for (int k = 0; k < 8; ++k) { am[k] = b2m[k]; ad[k] = b2d[k]; }

    // fused j-loop over both MLPs: weights are wave-uniform -> scalar loads
    #pragma unroll 2
    for (int j = 0; j < H_; ++j) {
        float pm = b1m[j], pd = b1d[j];
        #pragma unroll
        for (int k = 0; k < 8; ++k) {
            pm = fmaf(x[k], W1m[j*8 + k], pm);
            pd = fmaf(x[k], W1d[j*8 + k], pd);
        }
        const float hm = softplus_f(pm);
        const float hd = softplus_f(pd);
        #pragma unroll
        for (int k = 0; k < 8; ++k) {
            am[k] = fmaf(hm, W2m[k*H_ + j], am[k]);
            ad[k] = fmaf(hd, W2d[k*H_ + j], ad[k]);
        }
    }

    // load zt2 row late (reduces register liveness in main loop)
    float z2[8];
    {
        const float4* p = reinterpret_cast<const float4*>(zt2) + (size_t)i * 2;
        float4 a = p[0], b = p[1];
        z2[0]=a.x; z2[1]=a.y; z2[2]=a.z; z2[3]=a.w;
        z2[4]=b.x; z2[5]=b.y; z2[6]=b.z; z2[7]=b.w;
    }

    float t1 = 0.f, t2 = 0.f, t3 = 0.f, t4 = 0.f;
    float* __restrict__ mu_out = out + 1;
    float* __restrict__ sg_out = out + 1 + (size_t)BN * 8;
    #pragma unroll
    for (int k = 0; k < 8; ++k) {
        const float mu = am[k] * dt0;
        const float y  = ad[k];             // log(D) exactly (D = exp(y))
        const float Dk = __expf(y);
        const float iv = __expf(-2.0f * y); // 1/D^2
        const float dz = z2[k] - x[k];
        t1 += y;
        t2 = fmaf(dz * dz, iv, t2);
        t3 = fmaf(dz * mu, iv, t3);
        t4 = fmaf(mu * mu, iv, t4);
        mu_out[(size_t)i*8 + k] = mu;
        sg_out[(size_t)i*8 + k] = Dk * sqdt;
    }

    // loss contribution: -(const - 0.5*(t1+t2+t3+t4)), const = -4*log(2pi)
    constexpr float NEG_CONST = 7.3515082656373808f; // DIM/2 * log(2*pi)
    float nll = fmaf(0.5f, (2.0f*t1 + t2 - 2.0f*t3 + t4), NEG_CONST);

    // wave (64-lane) reduction, then block combine, one atomic per block
    #pragma unroll
    for (int off = 32; off > 0; off >>= 1) nll += __shfl_down(nll, off);

    __shared__ float wsum[4];
    const int lane = threadIdx.x & 63;
    const int wid  = threadIdx.x >> 6;
    if (lane == 0) wsum[wid] = nll;
    __syncthreads();
    if (threadIdx.x == 0) {
        atomicAdd(out, wsum[0] + wsum[1] + wsum[2] + wsum[3]);
    }
}

extern "C" void kernel_launch(void* const* d_in, const int* in_sizes, int n_in,
                              void* d_out, int out_size, void* d_ws, size_t ws_size,
                              hipStream_t stream) {
    // out[0] is the atomically-accumulated loss; harness poisons d_out with 0xAA
    hipMemsetAsync(d_out, 0, sizeof(float), stream);
    sde_fused<<<BN / 256, 256, 0, stream>>>(
        (const float*)d_in[0], (const float*)d_in[1], (const float*)d_in[2],
        (const float*)d_in[3], (const float*)d_in[4],
        (const float*)d_in[5], (const float*)d_in[6],
        (const float*)d_in[7], (const float*)d_in[8],
        (const float*)d_in[9], (const float*)d_in[10],
        (float*)d_out);
}